// Round 5
// baseline (555.850 us; speedup 1.0000x reference)
//
#include <hip/hip_runtime.h>

// VQ codebook: z_e [32,64,64,64] f32 (B,C,W,H), emb [1024,64] f32.
// Outputs: quantized [32,64,64,64] f32, indices [131072] (as f32), vq_loss [1].
//
// R5: bf16-split MFMA scan (3 cross-products hi/lo, f32 acc) + second-best
// margin test; points with approx gap <= DELTA are re-scanned with R1's exact
// f32 arithmetic (bit-identical to the absmax-0.0 kernel). Certain points'
// argmin provably equals the exact one (error bound << DELTA/2).

#define CDIM   64
#define KCODES 1024
#define NPTS   131072
#define WH     4096
#define CWH    262144
#define NBLK   (NPTS / 256)      // 512
#define CTILES (KCODES / 16)     // 64
#define DELTA  0.05f

typedef __attribute__((ext_vector_type(4))) float f32x4;
typedef __attribute__((ext_vector_type(8))) short bf16x8;

__device__ inline unsigned short f2bf(float f) {
    unsigned u = __float_as_uint(f);
    return (unsigned short)((u + 0x7FFFu + ((u >> 16) & 1u)) >> 16);
}
__device__ inline float bf2f(unsigned short h) {
    return __uint_as_float(((unsigned)h) << 16);
}

// ---------- E[k] = ||emb_k||^2 (exact f32, same as R1) ----------
__global__ __launch_bounds__(256) void vq_esq(const float* __restrict__ emb,
                                              float* __restrict__ E) {
    int k = blockIdx.x * 256 + threadIdx.x;
    if (k >= KCODES) return;
    const float4* e4 = (const float4*)(emb + k * CDIM);
    float s = 0.f;
#pragma unroll
    for (int i = 0; i < CDIM / 4; ++i) {
        float4 v = e4[i];
        s = fmaf(v.x, v.x, s); s = fmaf(v.y, v.y, s);
        s = fmaf(v.z, v.z, s); s = fmaf(v.w, v.w, s);
    }
    E[k] = s;
}

// ---------- e -> bf16 hi/lo in A-fragment-linear layout ----------
// chunk(ct, split, khalf) = 64 lanes x 8 ushort; lane l holds
// e_split[ct*16 + (l&15)][khalf*32 + (l>>4)*8 + j].
__global__ __launch_bounds__(256) void vq_eprep(const float* __restrict__ emb,
                                                unsigned short* __restrict__ e_swz) {
    int c = blockIdx.x * 256 + threadIdx.x;   // code
    if (c >= KCODES) return;
    int ct = c >> 4, col = c & 15;
#pragma unroll
    for (int kh = 0; kh < 2; ++kh)
#pragma unroll
        for (int g = 0; g < 4; ++g) {
            int lane = (g << 4) | col;
            size_t bh = ((size_t)(ct * 2 + 0) * 2 + kh) * 512 + (size_t)lane * 8;
            size_t bl = ((size_t)(ct * 2 + 1) * 2 + kh) * 512 + (size_t)lane * 8;
#pragma unroll
            for (int j = 0; j < 8; ++j) {
                float v = emb[c * CDIM + kh * 32 + g * 8 + j];
                unsigned short hi = f2bf(v);
                unsigned short lo = f2bf(v - bf2f(hi));
                e_swz[bh + j] = hi;
                e_swz[bl + j] = lo;
            }
        }
}

// ---------- MFMA scan: 128 points/block, all 1024 codes ----------
__global__ __launch_bounds__(256) void vq_scan_mfma(const float* __restrict__ z_e,
                                                    const unsigned short* __restrict__ e_swz,
                                                    const float* __restrict__ E,
                                                    int* __restrict__ bestk,
                                                    int* __restrict__ flagA) {
    const int tid = threadIdx.x;
    const int n0  = blockIdx.x * 128;
    const int b   = n0 >> 12;
    const int wh0 = n0 & 4095;

    // z fragments: [ptl 8][split 2][khalf 2][lane*8+j] (32 KB)
    __shared__ unsigned short zfrag[8][2][2][512];

    const float* zp = z_e + (size_t)b * CWH + wh0;
#pragma unroll 4
    for (int i = 0; i < 32; ++i) {
        int flat = i * 256 + tid;
        int c = flat >> 7, p = flat & 127;
        float v = zp[(size_t)c * WH + p];
        unsigned short hi = f2bf(v);
        unsigned short lo = f2bf(v - bf2f(hi));
        int slot = ((((c & 31) >> 3) << 4) | (p & 15)) * 8 + (c & 7);
        zfrag[p >> 4][0][c >> 5][slot] = hi;
        zfrag[p >> 4][1][c >> 5][slot] = lo;
    }
    __syncthreads();

    const int lane = tid & 63;
    const int w    = tid >> 6;

    bf16x8 zf[2][2][2];   // [pt][split][khalf] -- all indices compile-time
#pragma unroll
    for (int pt = 0; pt < 2; ++pt)
#pragma unroll
        for (int s = 0; s < 2; ++s)
#pragma unroll
            for (int kh = 0; kh < 2; ++kh)
                zf[pt][s][kh] = *(const bf16x8*)&zfrag[2 * w + pt][s][kh][lane * 8];

    const bf16x8* ebv = (const bf16x8*)e_swz;   // 64 x bf16x8 per chunk

    float m1a = 1e30f, m2a = 1e30f; int k1a = 0;
    float m1b = 1e30f, m2b = 1e30f; int k1b = 0;

    for (int ct = 0; ct < CTILES; ++ct) {
        bf16x8 eh0 = ebv[((ct * 2 + 0) * 2 + 0) * 64 + lane];
        bf16x8 eh1 = ebv[((ct * 2 + 0) * 2 + 1) * 64 + lane];
        bf16x8 el0 = ebv[((ct * 2 + 1) * 2 + 0) * 64 + lane];
        bf16x8 el1 = ebv[((ct * 2 + 1) * 2 + 1) * 64 + lane];

        f32x4 acc0 = {0.f, 0.f, 0.f, 0.f};
        f32x4 acc1 = {0.f, 0.f, 0.f, 0.f};
        // pt0: e_hi*z_hi (K=64) + e_hi*z_lo + e_lo*z_hi
        acc0 = __builtin_amdgcn_mfma_f32_16x16x32_bf16(eh0, zf[0][0][0], acc0, 0, 0, 0);
        acc0 = __builtin_amdgcn_mfma_f32_16x16x32_bf16(eh1, zf[0][0][1], acc0, 0, 0, 0);
        acc0 = __builtin_amdgcn_mfma_f32_16x16x32_bf16(eh0, zf[0][1][0], acc0, 0, 0, 0);
        acc0 = __builtin_amdgcn_mfma_f32_16x16x32_bf16(eh1, zf[0][1][1], acc0, 0, 0, 0);
        acc0 = __builtin_amdgcn_mfma_f32_16x16x32_bf16(el0, zf[0][0][0], acc0, 0, 0, 0);
        acc0 = __builtin_amdgcn_mfma_f32_16x16x32_bf16(el1, zf[0][0][1], acc0, 0, 0, 0);
        // pt1
        acc1 = __builtin_amdgcn_mfma_f32_16x16x32_bf16(eh0, zf[1][0][0], acc1, 0, 0, 0);
        acc1 = __builtin_amdgcn_mfma_f32_16x16x32_bf16(eh1, zf[1][0][1], acc1, 0, 0, 0);
        acc1 = __builtin_amdgcn_mfma_f32_16x16x32_bf16(eh0, zf[1][1][0], acc1, 0, 0, 0);
        acc1 = __builtin_amdgcn_mfma_f32_16x16x32_bf16(eh1, zf[1][1][1], acc1, 0, 0, 0);
        acc1 = __builtin_amdgcn_mfma_f32_16x16x32_bf16(el0, zf[1][0][0], acc1, 0, 0, 0);
        acc1 = __builtin_amdgcn_mfma_f32_16x16x32_bf16(el1, zf[1][0][1], acc1, 0, 0, 0);

        // D[row=(lane>>4)*4+i = code-in-tile][col=lane&15 = point-in-tile]
        const f32x4 Ev = *(const f32x4*)(E + ct * 16 + ((lane >> 4) << 2));
        const int kb = ct * 16 + ((lane >> 4) << 2);
#pragma unroll
        for (int i = 0; i < 4; ++i) {
            float s0 = fmaf(-2.0f, acc0[i], Ev[i]);
            if (s0 < m1a) { m2a = m1a; m1a = s0; k1a = kb + i; } else m2a = fminf(m2a, s0);
            float s1 = fmaf(-2.0f, acc1[i], Ev[i]);
            if (s1 < m1b) { m2b = m1b; m1b = s1; k1b = kb + i; } else m2b = fminf(m2b, s1);
        }
    }

    // lanes {l, l^16, l^32, l^48} hold the same point's 4 row-groups
#pragma unroll
    for (int d = 16; d <= 32; d <<= 1) {
        float om1 = __shfl_xor(m1a, d); int ok1 = __shfl_xor(k1a, d); float om2 = __shfl_xor(m2a, d);
        bool take = (om1 < m1a) || (om1 == m1a && ok1 < k1a);
        float nm2 = take ? fminf(m1a, om2) : fminf(m2a, om1);
        if (take) { m1a = om1; k1a = ok1; }
        m2a = nm2;
        om1 = __shfl_xor(m1b, d); ok1 = __shfl_xor(k1b, d); om2 = __shfl_xor(m2b, d);
        take = (om1 < m1b) || (om1 == m1b && ok1 < k1b);
        nm2 = take ? fminf(m1b, om2) : fminf(m2b, om1);
        if (take) { m1b = om1; k1b = ok1; }
        m2b = nm2;
    }

    if (lane < 16) {
        int na  = n0 + (2 * w + 0) * 16 + lane;
        int nb_ = n0 + (2 * w + 1) * 16 + lane;
        bestk[na]  = k1a; flagA[na]  = (m2a - m1a <= DELTA) ? 1 : 0;
        bestk[nb_] = k1b; flagA[nb_] = (m2b - m1b <= DELTA) ? 1 : 0;
    }
}

// ---------- rescue plumbing ----------
__global__ void vq_zero(int* cnt) {
    if (blockIdx.x == 0 && threadIdx.x == 0) cnt[0] = 0;
}
__global__ __launch_bounds__(256) void vq_compact(const int* __restrict__ flagA,
                                                  int* __restrict__ list,
                                                  int* __restrict__ cnt) {
    int n = blockIdx.x * 256 + threadIdx.x;
    if (n < NPTS && flagA[n]) { int p = atomicAdd(cnt, 1); list[p] = n; }
}

// Exact f32 re-scan (bit-identical to R1's absmax-0.0 arithmetic).
__global__ __launch_bounds__(256) void vq_rescue(const float* __restrict__ z_e,
                                                 const float* __restrict__ emb,
                                                 const float* __restrict__ E,
                                                 const int* __restrict__ list,
                                                 const int* __restrict__ cnt,
                                                 int* __restrict__ bestk) {
    const int total  = cnt[0];
    const int stride = 256 * 128;
    for (int i = blockIdx.x * 256 + threadIdx.x; i < total; i += stride) {
        int n  = list[i];
        int b  = n >> 12, wh = n & 4095;
        const float* zp = z_e + (size_t)b * CWH + wh;
        float z[CDIM];
#pragma unroll
        for (int c = 0; c < CDIM; ++c) z[c] = zp[c * WH];
        float best = 1e30f; int bk = 0;
        for (int k = 0; k < KCODES; ++k) {
            const float* er = emb + k * CDIM;
            float d0 = 0.f, d1 = 0.f, d2 = 0.f, d3 = 0.f;
#pragma unroll
            for (int c = 0; c < CDIM; c += 4) {
                d0 = fmaf(z[c + 0], er[c + 0], d0);
                d1 = fmaf(z[c + 1], er[c + 1], d1);
                d2 = fmaf(z[c + 2], er[c + 2], d2);
                d3 = fmaf(z[c + 3], er[c + 3], d3);
            }
            float dot   = (d0 + d1) + (d2 + d3);
            float score = fmaf(-2.0f, dot, E[k]);
            if (score < best) { best = score; bk = k; }
        }
        bestk[n] = bk;
    }
}

// ---------- gather + q/idx write + loss (same arithmetic as R3/R4) ----------
__global__ __launch_bounds__(256) void vq_merge(const float* __restrict__ z_e,
                                                const float* __restrict__ emb,
                                                const int* __restrict__ kf,
                                                float* __restrict__ out_q,
                                                float* __restrict__ out_idx,
                                                float* __restrict__ partials) {
    const int tid = threadIdx.x;
    const int n   = blockIdx.x * 256 + tid;
    const int b   = n >> 12;
    const int wh  = n & 4095;

    int mk = kf[n];
    out_idx[n] = (float)mk;

    const float* eb = emb + mk * CDIM;
    const float* zp = z_e + (size_t)b * CWH + wh;
    float* qp = out_q + (size_t)b * CWH + wh;
    float lsum = 0.f;
#pragma unroll
    for (int c = 0; c < CDIM; ++c) {
        float ev = eb[c];
        qp[c * WH] = ev;
        float d = ev - zp[c * WH];
        lsum = fmaf(d, d, lsum);
    }

    __shared__ float red[256];
    red[tid] = lsum;
    __syncthreads();
    for (int s = 128; s > 0; s >>= 1) {
        if (tid < s) red[tid] += red[tid + s];
        __syncthreads();
    }
    if (tid == 0) partials[blockIdx.x] = red[0];
}

__global__ __launch_bounds__(512) void vq_loss_fin(const float* __restrict__ partials,
                                                   float* __restrict__ loss) {
    __shared__ float red[NBLK];
    int t = threadIdx.x;
    red[t] = partials[t];
    __syncthreads();
    for (int s = NBLK / 2; s > 0; s >>= 1) {
        if (t < s) red[t] += red[t + s];
        __syncthreads();
    }
    if (t == 0) loss[0] = red[0] * (1.25f / 8388608.0f);
}

extern "C" void kernel_launch(void* const* d_in, const int* in_sizes, int n_in,
                              void* d_out, int out_size, void* d_ws, size_t ws_size,
                              hipStream_t stream) {
    const float* z_e = (const float*)d_in[0];
    const float* emb = (const float*)d_in[1];

    float* out      = (float*)d_out;
    float* out_q    = out;
    float* out_idx  = out + 8388608;
    float* out_loss = out + 8388608 + 131072;

    char* w = (char*)d_ws;
    float*          E        = (float*)(w);                    //   4 KB
    unsigned short* e_swz    = (unsigned short*)(w + 4096);    // 256 KB
    int*            bestk    = (int*)(w + 266240);             // 512 KB
    int*            flagA    = (int*)(w + 790528);             // 512 KB
    int*            list     = (int*)(w + 1314816);            // 512 KB
    int*            cnt      = (int*)(w + 1839104);
    float*          partials = (float*)(w + 1840128);          //   2 KB

    vq_esq<<<KCODES / 256, 256, 0, stream>>>(emb, E);
    vq_eprep<<<KCODES / 256, 256, 0, stream>>>(emb, e_swz);
    vq_zero<<<1, 64, 0, stream>>>(cnt);
    vq_scan_mfma<<<NPTS / 128, 256, 0, stream>>>(z_e, e_swz, E, bestk, flagA);
    vq_compact<<<NPTS / 256, 256, 0, stream>>>(flagA, list, cnt);
    vq_rescue<<<128, 256, 0, stream>>>(z_e, emb, E, list, cnt, bestk);
    vq_merge<<<NBLK, 256, 0, stream>>>(z_e, emb, bestk, out_q, out_idx, partials);
    vq_loss_fin<<<1, NBLK, 0, stream>>>(partials, out_loss);
}

// Round 6
// 203.520 us; speedup vs baseline: 2.7312x; 2.7312x over previous
//
#include <hip/hip_runtime.h>

// VQ codebook: z_e [32,64,64,64] f32 (B,C,W,H), emb [1024,64] f32.
// Outputs: quantized [32,64,64,64] f32, indices [131072] (as f32), vq_loss [1].
//
// R6: same as R5 (bf16-split MFMA scan + margin test + exact-f32 rescue) but
// the rescue is wave-parallel: one wave per flagged point, lane l scans codes
// l*16..l*16+15 with R1's bit-identical per-k arithmetic, then a lexicographic
// (score,k) butterfly reduce == global first-min. R5's rescue was 450us of
// pure serial latency (1 thread/point, 0.5% occupancy).

#define CDIM   64
#define KCODES 1024
#define NPTS   131072
#define WH     4096
#define CWH    262144
#define NBLK   (NPTS / 256)      // 512
#define CTILES (KCODES / 16)     // 64
#define DELTA  0.05f

typedef __attribute__((ext_vector_type(4))) float f32x4;
typedef __attribute__((ext_vector_type(8))) short bf16x8;

__device__ inline unsigned short f2bf(float f) {
    unsigned u = __float_as_uint(f);
    return (unsigned short)((u + 0x7FFFu + ((u >> 16) & 1u)) >> 16);
}
__device__ inline float bf2f(unsigned short h) {
    return __uint_as_float(((unsigned)h) << 16);
}

// ---------- E[k] = ||emb_k||^2 (exact f32, same as R1) ----------
__global__ __launch_bounds__(256) void vq_esq(const float* __restrict__ emb,
                                              float* __restrict__ E) {
    int k = blockIdx.x * 256 + threadIdx.x;
    if (k >= KCODES) return;
    const float4* e4 = (const float4*)(emb + k * CDIM);
    float s = 0.f;
#pragma unroll
    for (int i = 0; i < CDIM / 4; ++i) {
        float4 v = e4[i];
        s = fmaf(v.x, v.x, s); s = fmaf(v.y, v.y, s);
        s = fmaf(v.z, v.z, s); s = fmaf(v.w, v.w, s);
    }
    E[k] = s;
}

// ---------- e -> bf16 hi/lo in A-fragment-linear layout ----------
__global__ __launch_bounds__(256) void vq_eprep(const float* __restrict__ emb,
                                                unsigned short* __restrict__ e_swz) {
    int c = blockIdx.x * 256 + threadIdx.x;   // code
    if (c >= KCODES) return;
    int ct = c >> 4, col = c & 15;
#pragma unroll
    for (int kh = 0; kh < 2; ++kh)
#pragma unroll
        for (int g = 0; g < 4; ++g) {
            int lane = (g << 4) | col;
            size_t bh = ((size_t)(ct * 2 + 0) * 2 + kh) * 512 + (size_t)lane * 8;
            size_t bl = ((size_t)(ct * 2 + 1) * 2 + kh) * 512 + (size_t)lane * 8;
#pragma unroll
            for (int j = 0; j < 8; ++j) {
                float v = emb[c * CDIM + kh * 32 + g * 8 + j];
                unsigned short hi = f2bf(v);
                unsigned short lo = f2bf(v - bf2f(hi));
                e_swz[bh + j] = hi;
                e_swz[bl + j] = lo;
            }
        }
}

// ---------- MFMA scan: 128 points/block, all 1024 codes ----------
__global__ __launch_bounds__(256) void vq_scan_mfma(const float* __restrict__ z_e,
                                                    const unsigned short* __restrict__ e_swz,
                                                    const float* __restrict__ E,
                                                    int* __restrict__ bestk,
                                                    int* __restrict__ flagA) {
    const int tid = threadIdx.x;
    const int n0  = blockIdx.x * 128;
    const int b   = n0 >> 12;
    const int wh0 = n0 & 4095;

    __shared__ unsigned short zfrag[8][2][2][512];   // 32 KB

    const float* zp = z_e + (size_t)b * CWH + wh0;
#pragma unroll 4
    for (int i = 0; i < 32; ++i) {
        int flat = i * 256 + tid;
        int c = flat >> 7, p = flat & 127;
        float v = zp[(size_t)c * WH + p];
        unsigned short hi = f2bf(v);
        unsigned short lo = f2bf(v - bf2f(hi));
        int slot = ((((c & 31) >> 3) << 4) | (p & 15)) * 8 + (c & 7);
        zfrag[p >> 4][0][c >> 5][slot] = hi;
        zfrag[p >> 4][1][c >> 5][slot] = lo;
    }
    __syncthreads();

    const int lane = tid & 63;
    const int w    = tid >> 6;

    bf16x8 zf[2][2][2];
#pragma unroll
    for (int pt = 0; pt < 2; ++pt)
#pragma unroll
        for (int s = 0; s < 2; ++s)
#pragma unroll
            for (int kh = 0; kh < 2; ++kh)
                zf[pt][s][kh] = *(const bf16x8*)&zfrag[2 * w + pt][s][kh][lane * 8];

    const bf16x8* ebv = (const bf16x8*)e_swz;

    float m1a = 1e30f, m2a = 1e30f; int k1a = 0;
    float m1b = 1e30f, m2b = 1e30f; int k1b = 0;

    for (int ct = 0; ct < CTILES; ++ct) {
        bf16x8 eh0 = ebv[((ct * 2 + 0) * 2 + 0) * 64 + lane];
        bf16x8 eh1 = ebv[((ct * 2 + 0) * 2 + 1) * 64 + lane];
        bf16x8 el0 = ebv[((ct * 2 + 1) * 2 + 0) * 64 + lane];
        bf16x8 el1 = ebv[((ct * 2 + 1) * 2 + 1) * 64 + lane];

        f32x4 acc0 = {0.f, 0.f, 0.f, 0.f};
        f32x4 acc1 = {0.f, 0.f, 0.f, 0.f};
        acc0 = __builtin_amdgcn_mfma_f32_16x16x32_bf16(eh0, zf[0][0][0], acc0, 0, 0, 0);
        acc0 = __builtin_amdgcn_mfma_f32_16x16x32_bf16(eh1, zf[0][0][1], acc0, 0, 0, 0);
        acc0 = __builtin_amdgcn_mfma_f32_16x16x32_bf16(eh0, zf[0][1][0], acc0, 0, 0, 0);
        acc0 = __builtin_amdgcn_mfma_f32_16x16x32_bf16(eh1, zf[0][1][1], acc0, 0, 0, 0);
        acc0 = __builtin_amdgcn_mfma_f32_16x16x32_bf16(el0, zf[0][0][0], acc0, 0, 0, 0);
        acc0 = __builtin_amdgcn_mfma_f32_16x16x32_bf16(el1, zf[0][0][1], acc0, 0, 0, 0);
        acc1 = __builtin_amdgcn_mfma_f32_16x16x32_bf16(eh0, zf[1][0][0], acc1, 0, 0, 0);
        acc1 = __builtin_amdgcn_mfma_f32_16x16x32_bf16(eh1, zf[1][0][1], acc1, 0, 0, 0);
        acc1 = __builtin_amdgcn_mfma_f32_16x16x32_bf16(eh0, zf[1][1][0], acc1, 0, 0, 0);
        acc1 = __builtin_amdgcn_mfma_f32_16x16x32_bf16(eh1, zf[1][1][1], acc1, 0, 0, 0);
        acc1 = __builtin_amdgcn_mfma_f32_16x16x32_bf16(el0, zf[1][0][0], acc1, 0, 0, 0);
        acc1 = __builtin_amdgcn_mfma_f32_16x16x32_bf16(el1, zf[1][0][1], acc1, 0, 0, 0);

        const f32x4 Ev = *(const f32x4*)(E + ct * 16 + ((lane >> 4) << 2));
        const int kb = ct * 16 + ((lane >> 4) << 2);
#pragma unroll
        for (int i = 0; i < 4; ++i) {
            float s0 = fmaf(-2.0f, acc0[i], Ev[i]);
            if (s0 < m1a) { m2a = m1a; m1a = s0; k1a = kb + i; } else m2a = fminf(m2a, s0);
            float s1 = fmaf(-2.0f, acc1[i], Ev[i]);
            if (s1 < m1b) { m2b = m1b; m1b = s1; k1b = kb + i; } else m2b = fminf(m2b, s1);
        }
    }

#pragma unroll
    for (int d = 16; d <= 32; d <<= 1) {
        float om1 = __shfl_xor(m1a, d); int ok1 = __shfl_xor(k1a, d); float om2 = __shfl_xor(m2a, d);
        bool take = (om1 < m1a) || (om1 == m1a && ok1 < k1a);
        float nm2 = take ? fminf(m1a, om2) : fminf(m2a, om1);
        if (take) { m1a = om1; k1a = ok1; }
        m2a = nm2;
        om1 = __shfl_xor(m1b, d); ok1 = __shfl_xor(k1b, d); om2 = __shfl_xor(m2b, d);
        take = (om1 < m1b) || (om1 == m1b && ok1 < k1b);
        nm2 = take ? fminf(m1b, om2) : fminf(m2b, om1);
        if (take) { m1b = om1; k1b = ok1; }
        m2b = nm2;
    }

    if (lane < 16) {
        int na  = n0 + (2 * w + 0) * 16 + lane;
        int nb_ = n0 + (2 * w + 1) * 16 + lane;
        bestk[na]  = k1a; flagA[na]  = (m2a - m1a <= DELTA) ? 1 : 0;
        bestk[nb_] = k1b; flagA[nb_] = (m2b - m1b <= DELTA) ? 1 : 0;
    }
}

// ---------- rescue plumbing ----------
__global__ void vq_zero(int* cnt) {
    if (blockIdx.x == 0 && threadIdx.x == 0) cnt[0] = 0;
}
__global__ __launch_bounds__(256) void vq_compact(const int* __restrict__ flagA,
                                                  int* __restrict__ list,
                                                  int* __restrict__ cnt) {
    int n = blockIdx.x * 256 + threadIdx.x;
    if (n < NPTS && flagA[n]) { int p = atomicAdd(cnt, 1); list[p] = n; }
}

// Wave-parallel exact f32 rescue: one wave per flagged point, lane l scans
// k = l*16..l*16+15 with R1's bit-identical per-k arithmetic; lexicographic
// (score,k) butterfly == global first-min (jnp.argmin tie-break).
__global__ __launch_bounds__(256) void vq_rescue(const float* __restrict__ z_e,
                                                 const float* __restrict__ emb,
                                                 const float* __restrict__ E,
                                                 const int* __restrict__ list,
                                                 const int* __restrict__ cnt,
                                                 int* __restrict__ bestk) {
    const int total  = cnt[0];
    const int lane   = threadIdx.x & 63;
    const int wid    = (blockIdx.x * 256 + threadIdx.x) >> 6;
    const int nwaves = (gridDim.x * 256) >> 6;

    for (int i = wid; i < total; i += nwaves) {
        const int n  = list[i];
        const int b  = n >> 12, wh = n & 4095;
        const float* zp = z_e + (size_t)b * CWH + wh;
        float z[CDIM];
#pragma unroll
        for (int c = 0; c < CDIM; ++c) z[c] = zp[c * WH];

        float best = 1e30f; int bk = 0;
        const int kbase = lane * 16;
#pragma unroll 2
        for (int j = 0; j < 16; ++j) {
            const int k = kbase + j;
            const float* er = emb + k * CDIM;
            float d0 = 0.f, d1 = 0.f, d2 = 0.f, d3 = 0.f;
#pragma unroll
            for (int c = 0; c < CDIM; c += 4) {
                d0 = fmaf(z[c + 0], er[c + 0], d0);
                d1 = fmaf(z[c + 1], er[c + 1], d1);
                d2 = fmaf(z[c + 2], er[c + 2], d2);
                d3 = fmaf(z[c + 3], er[c + 3], d3);
            }
            float dot   = (d0 + d1) + (d2 + d3);
            float score = fmaf(-2.0f, dot, E[k]);
            if (score < best) { best = score; bk = k; }   // ascending k in lane
        }
#pragma unroll
        for (int d = 1; d < 64; d <<= 1) {
            float ob = __shfl_xor(best, d);
            int   ok = __shfl_xor(bk, d);
            if (ob < best || (ob == best && ok < bk)) { best = ob; bk = ok; }
        }
        if (lane == 0) bestk[n] = bk;
    }
}

// ---------- gather + q/idx write + loss (same arithmetic as R3-R5) ----------
__global__ __launch_bounds__(256) void vq_merge(const float* __restrict__ z_e,
                                                const float* __restrict__ emb,
                                                const int* __restrict__ kf,
                                                float* __restrict__ out_q,
                                                float* __restrict__ out_idx,
                                                float* __restrict__ partials) {
    const int tid = threadIdx.x;
    const int n   = blockIdx.x * 256 + tid;
    const int b   = n >> 12;
    const int wh  = n & 4095;

    int mk = kf[n];
    out_idx[n] = (float)mk;

    const float* eb = emb + mk * CDIM;
    const float* zp = z_e + (size_t)b * CWH + wh;
    float* qp = out_q + (size_t)b * CWH + wh;
    float lsum = 0.f;
#pragma unroll
    for (int c = 0; c < CDIM; ++c) {
        float ev = eb[c];
        qp[c * WH] = ev;
        float d = ev - zp[c * WH];
        lsum = fmaf(d, d, lsum);
    }

    __shared__ float red[256];
    red[tid] = lsum;
    __syncthreads();
    for (int s = 128; s > 0; s >>= 1) {
        if (tid < s) red[tid] += red[tid + s];
        __syncthreads();
    }
    if (tid == 0) partials[blockIdx.x] = red[0];
}

__global__ __launch_bounds__(512) void vq_loss_fin(const float* __restrict__ partials,
                                                   float* __restrict__ loss) {
    __shared__ float red[NBLK];
    int t = threadIdx.x;
    red[t] = partials[t];
    __syncthreads();
    for (int s = NBLK / 2; s > 0; s >>= 1) {
        if (t < s) red[t] += red[t + s];
        __syncthreads();
    }
    if (t == 0) loss[0] = red[0] * (1.25f / 8388608.0f);
}

extern "C" void kernel_launch(void* const* d_in, const int* in_sizes, int n_in,
                              void* d_out, int out_size, void* d_ws, size_t ws_size,
                              hipStream_t stream) {
    const float* z_e = (const float*)d_in[0];
    const float* emb = (const float*)d_in[1];

    float* out      = (float*)d_out;
    float* out_q    = out;
    float* out_idx  = out + 8388608;
    float* out_loss = out + 8388608 + 131072;

    char* w = (char*)d_ws;
    float*          E        = (float*)(w);                    //   4 KB
    unsigned short* e_swz    = (unsigned short*)(w + 4096);    // 256 KB
    int*            bestk    = (int*)(w + 266240);             // 512 KB
    int*            flagA    = (int*)(w + 790528);             // 512 KB
    int*            list     = (int*)(w + 1314816);            // 512 KB
    int*            cnt      = (int*)(w + 1839104);
    float*          partials = (float*)(w + 1840128);          //   2 KB

    vq_esq<<<KCODES / 256, 256, 0, stream>>>(emb, E);
    vq_eprep<<<KCODES / 256, 256, 0, stream>>>(emb, e_swz);
    vq_zero<<<1, 64, 0, stream>>>(cnt);
    vq_scan_mfma<<<NPTS / 128, 256, 0, stream>>>(z_e, e_swz, E, bestk, flagA);
    vq_compact<<<NPTS / 256, 256, 0, stream>>>(flagA, list, cnt);
    vq_rescue<<<512, 256, 0, stream>>>(z_e, emb, E, list, cnt, bestk);
    vq_merge<<<NBLK, 256, 0, stream>>>(z_e, emb, bestk, out_q, out_idx, partials);
    vq_loss_fin<<<1, NBLK, 0, stream>>>(partials, out_loss);
}

// Round 7
// 161.698 us; speedup vs baseline: 3.4376x; 1.2586x over previous
//
#include <hip/hip_runtime.h>

// VQ codebook: z_e [32,64,64,64] f32 (B,C,W,H), emb [1024,64] f32.
// Outputs: quantized [32,64,64,64] f32, indices [131072] (as f32), vq_loss [1].
//
// R7 = R6 with a cheaper rescue:
//  - DELTA 0.05 -> 0.02 (per-score error bound ~2e-3; 2*eps = 4e-3, 5x margin)
//  - rescue grid 512 -> 2048 blocks (8192 waves; R6 had 2 waves/SIMD, gather
//    latency unhidden -> VALUBusy 6.4%)
//  - rescue code-row loads as float4 (4x fewer 64-line gather instructions),
//    fmaf chains bit-identical to R1.

#define CDIM   64
#define KCODES 1024
#define NPTS   131072
#define WH     4096
#define CWH    262144
#define NBLK   (NPTS / 256)      // 512
#define CTILES (KCODES / 16)     // 64
#define DELTA  0.02f

typedef __attribute__((ext_vector_type(4))) float f32x4;
typedef __attribute__((ext_vector_type(8))) short bf16x8;

__device__ inline unsigned short f2bf(float f) {
    unsigned u = __float_as_uint(f);
    return (unsigned short)((u + 0x7FFFu + ((u >> 16) & 1u)) >> 16);
}
__device__ inline float bf2f(unsigned short h) {
    return __uint_as_float(((unsigned)h) << 16);
}

// ---------- E[k] = ||emb_k||^2 (exact f32, same as R1) ----------
__global__ __launch_bounds__(256) void vq_esq(const float* __restrict__ emb,
                                              float* __restrict__ E) {
    int k = blockIdx.x * 256 + threadIdx.x;
    if (k >= KCODES) return;
    const float4* e4 = (const float4*)(emb + k * CDIM);
    float s = 0.f;
#pragma unroll
    for (int i = 0; i < CDIM / 4; ++i) {
        float4 v = e4[i];
        s = fmaf(v.x, v.x, s); s = fmaf(v.y, v.y, s);
        s = fmaf(v.z, v.z, s); s = fmaf(v.w, v.w, s);
    }
    E[k] = s;
}

// ---------- e -> bf16 hi/lo in A-fragment-linear layout ----------
__global__ __launch_bounds__(256) void vq_eprep(const float* __restrict__ emb,
                                                unsigned short* __restrict__ e_swz) {
    int c = blockIdx.x * 256 + threadIdx.x;   // code
    if (c >= KCODES) return;
    int ct = c >> 4, col = c & 15;
#pragma unroll
    for (int kh = 0; kh < 2; ++kh)
#pragma unroll
        for (int g = 0; g < 4; ++g) {
            int lane = (g << 4) | col;
            size_t bh = ((size_t)(ct * 2 + 0) * 2 + kh) * 512 + (size_t)lane * 8;
            size_t bl = ((size_t)(ct * 2 + 1) * 2 + kh) * 512 + (size_t)lane * 8;
#pragma unroll
            for (int j = 0; j < 8; ++j) {
                float v = emb[c * CDIM + kh * 32 + g * 8 + j];
                unsigned short hi = f2bf(v);
                unsigned short lo = f2bf(v - bf2f(hi));
                e_swz[bh + j] = hi;
                e_swz[bl + j] = lo;
            }
        }
}

// ---------- MFMA scan: 128 points/block, all 1024 codes ----------
__global__ __launch_bounds__(256) void vq_scan_mfma(const float* __restrict__ z_e,
                                                    const unsigned short* __restrict__ e_swz,
                                                    const float* __restrict__ E,
                                                    int* __restrict__ bestk,
                                                    int* __restrict__ flagA) {
    const int tid = threadIdx.x;
    const int n0  = blockIdx.x * 128;
    const int b   = n0 >> 12;
    const int wh0 = n0 & 4095;

    __shared__ unsigned short zfrag[8][2][2][512];   // 32 KB

    const float* zp = z_e + (size_t)b * CWH + wh0;
#pragma unroll 4
    for (int i = 0; i < 32; ++i) {
        int flat = i * 256 + tid;
        int c = flat >> 7, p = flat & 127;
        float v = zp[(size_t)c * WH + p];
        unsigned short hi = f2bf(v);
        unsigned short lo = f2bf(v - bf2f(hi));
        int slot = ((((c & 31) >> 3) << 4) | (p & 15)) * 8 + (c & 7);
        zfrag[p >> 4][0][c >> 5][slot] = hi;
        zfrag[p >> 4][1][c >> 5][slot] = lo;
    }
    __syncthreads();

    const int lane = tid & 63;
    const int w    = tid >> 6;

    bf16x8 zf[2][2][2];
#pragma unroll
    for (int pt = 0; pt < 2; ++pt)
#pragma unroll
        for (int s = 0; s < 2; ++s)
#pragma unroll
            for (int kh = 0; kh < 2; ++kh)
                zf[pt][s][kh] = *(const bf16x8*)&zfrag[2 * w + pt][s][kh][lane * 8];

    const bf16x8* ebv = (const bf16x8*)e_swz;

    float m1a = 1e30f, m2a = 1e30f; int k1a = 0;
    float m1b = 1e30f, m2b = 1e30f; int k1b = 0;

    for (int ct = 0; ct < CTILES; ++ct) {
        bf16x8 eh0 = ebv[((ct * 2 + 0) * 2 + 0) * 64 + lane];
        bf16x8 eh1 = ebv[((ct * 2 + 0) * 2 + 1) * 64 + lane];
        bf16x8 el0 = ebv[((ct * 2 + 1) * 2 + 0) * 64 + lane];
        bf16x8 el1 = ebv[((ct * 2 + 1) * 2 + 1) * 64 + lane];

        f32x4 acc0 = {0.f, 0.f, 0.f, 0.f};
        f32x4 acc1 = {0.f, 0.f, 0.f, 0.f};
        acc0 = __builtin_amdgcn_mfma_f32_16x16x32_bf16(eh0, zf[0][0][0], acc0, 0, 0, 0);
        acc0 = __builtin_amdgcn_mfma_f32_16x16x32_bf16(eh1, zf[0][0][1], acc0, 0, 0, 0);
        acc0 = __builtin_amdgcn_mfma_f32_16x16x32_bf16(eh0, zf[0][1][0], acc0, 0, 0, 0);
        acc0 = __builtin_amdgcn_mfma_f32_16x16x32_bf16(eh1, zf[0][1][1], acc0, 0, 0, 0);
        acc0 = __builtin_amdgcn_mfma_f32_16x16x32_bf16(el0, zf[0][0][0], acc0, 0, 0, 0);
        acc0 = __builtin_amdgcn_mfma_f32_16x16x32_bf16(el1, zf[0][0][1], acc0, 0, 0, 0);
        acc1 = __builtin_amdgcn_mfma_f32_16x16x32_bf16(eh0, zf[1][0][0], acc1, 0, 0, 0);
        acc1 = __builtin_amdgcn_mfma_f32_16x16x32_bf16(eh1, zf[1][0][1], acc1, 0, 0, 0);
        acc1 = __builtin_amdgcn_mfma_f32_16x16x32_bf16(eh0, zf[1][1][0], acc1, 0, 0, 0);
        acc1 = __builtin_amdgcn_mfma_f32_16x16x32_bf16(eh1, zf[1][1][1], acc1, 0, 0, 0);
        acc1 = __builtin_amdgcn_mfma_f32_16x16x32_bf16(el0, zf[1][0][0], acc1, 0, 0, 0);
        acc1 = __builtin_amdgcn_mfma_f32_16x16x32_bf16(el1, zf[1][0][1], acc1, 0, 0, 0);

        const f32x4 Ev = *(const f32x4*)(E + ct * 16 + ((lane >> 4) << 2));
        const int kb = ct * 16 + ((lane >> 4) << 2);
#pragma unroll
        for (int i = 0; i < 4; ++i) {
            float s0 = fmaf(-2.0f, acc0[i], Ev[i]);
            if (s0 < m1a) { m2a = m1a; m1a = s0; k1a = kb + i; } else m2a = fminf(m2a, s0);
            float s1 = fmaf(-2.0f, acc1[i], Ev[i]);
            if (s1 < m1b) { m2b = m1b; m1b = s1; k1b = kb + i; } else m2b = fminf(m2b, s1);
        }
    }

#pragma unroll
    for (int d = 16; d <= 32; d <<= 1) {
        float om1 = __shfl_xor(m1a, d); int ok1 = __shfl_xor(k1a, d); float om2 = __shfl_xor(m2a, d);
        bool take = (om1 < m1a) || (om1 == m1a && ok1 < k1a);
        float nm2 = take ? fminf(m1a, om2) : fminf(m2a, om1);
        if (take) { m1a = om1; k1a = ok1; }
        m2a = nm2;
        om1 = __shfl_xor(m1b, d); ok1 = __shfl_xor(k1b, d); om2 = __shfl_xor(m2b, d);
        take = (om1 < m1b) || (om1 == m1b && ok1 < k1b);
        nm2 = take ? fminf(m1b, om2) : fminf(m2b, om1);
        if (take) { m1b = om1; k1b = ok1; }
        m2b = nm2;
    }

    if (lane < 16) {
        int na  = n0 + (2 * w + 0) * 16 + lane;
        int nb_ = n0 + (2 * w + 1) * 16 + lane;
        bestk[na]  = k1a; flagA[na]  = (m2a - m1a <= DELTA) ? 1 : 0;
        bestk[nb_] = k1b; flagA[nb_] = (m2b - m1b <= DELTA) ? 1 : 0;
    }
}

// ---------- rescue plumbing ----------
__global__ void vq_zero(int* cnt) {
    if (blockIdx.x == 0 && threadIdx.x == 0) cnt[0] = 0;
}
__global__ __launch_bounds__(256) void vq_compact(const int* __restrict__ flagA,
                                                  int* __restrict__ list,
                                                  int* __restrict__ cnt) {
    int n = blockIdx.x * 256 + threadIdx.x;
    if (n < NPTS && flagA[n]) { int p = atomicAdd(cnt, 1); list[p] = n; }
}

// Wave-parallel exact f32 rescue: one wave per flagged point, lane l scans
// k = l*16..l*16+15 with R1's bit-identical per-k arithmetic (float4 loads,
// same fmaf chains); lexicographic (score,k) butterfly == global first-min.
__global__ __launch_bounds__(256) void vq_rescue(const float* __restrict__ z_e,
                                                 const float* __restrict__ emb,
                                                 const float* __restrict__ E,
                                                 const int* __restrict__ list,
                                                 const int* __restrict__ cnt,
                                                 int* __restrict__ bestk) {
    const int total  = cnt[0];
    const int lane   = threadIdx.x & 63;
    const int wid    = (blockIdx.x * 256 + threadIdx.x) >> 6;
    const int nwaves = (gridDim.x * 256) >> 6;

    for (int i = wid; i < total; i += nwaves) {
        const int n  = list[i];
        const int b  = n >> 12, wh = n & 4095;
        const float* zp = z_e + (size_t)b * CWH + wh;
        float z[CDIM];
#pragma unroll
        for (int c = 0; c < CDIM; ++c) z[c] = zp[c * WH];

        float best = 1e30f; int bk = 0;
        const int kbase = lane * 16;
#pragma unroll 4
        for (int j = 0; j < 16; ++j) {
            const int k = kbase + j;
            const float4* er4 = (const float4*)(emb + k * CDIM);
            float d0 = 0.f, d1 = 0.f, d2 = 0.f, d3 = 0.f;
#pragma unroll
            for (int c4 = 0; c4 < CDIM / 4; ++c4) {
                float4 v = er4[c4];
                d0 = fmaf(z[4 * c4 + 0], v.x, d0);
                d1 = fmaf(z[4 * c4 + 1], v.y, d1);
                d2 = fmaf(z[4 * c4 + 2], v.z, d2);
                d3 = fmaf(z[4 * c4 + 3], v.w, d3);
            }
            float dot   = (d0 + d1) + (d2 + d3);
            float score = fmaf(-2.0f, dot, E[k]);
            if (score < best) { best = score; bk = k; }   // ascending k in lane
        }
#pragma unroll
        for (int d = 1; d < 64; d <<= 1) {
            float ob = __shfl_xor(best, d);
            int   ok = __shfl_xor(bk, d);
            if (ob < best || (ob == best && ok < bk)) { best = ob; bk = ok; }
        }
        if (lane == 0) bestk[n] = bk;
    }
}

// ---------- gather + q/idx write + loss (same arithmetic as R3-R6) ----------
__global__ __launch_bounds__(256) void vq_merge(const float* __restrict__ z_e,
                                                const float* __restrict__ emb,
                                                const int* __restrict__ kf,
                                                float* __restrict__ out_q,
                                                float* __restrict__ out_idx,
                                                float* __restrict__ partials) {
    const int tid = threadIdx.x;
    const int n   = blockIdx.x * 256 + tid;
    const int b   = n >> 12;
    const int wh  = n & 4095;

    int mk = kf[n];
    out_idx[n] = (float)mk;

    const float* eb = emb + mk * CDIM;
    const float* zp = z_e + (size_t)b * CWH + wh;
    float* qp = out_q + (size_t)b * CWH + wh;
    float lsum = 0.f;
#pragma unroll
    for (int c = 0; c < CDIM; ++c) {
        float ev = eb[c];
        qp[c * WH] = ev;
        float d = ev - zp[c * WH];
        lsum = fmaf(d, d, lsum);
    }

    __shared__ float red[256];
    red[tid] = lsum;
    __syncthreads();
    for (int s = 128; s > 0; s >>= 1) {
        if (tid < s) red[tid] += red[tid + s];
        __syncthreads();
    }
    if (tid == 0) partials[blockIdx.x] = red[0];
}

__global__ __launch_bounds__(512) void vq_loss_fin(const float* __restrict__ partials,
                                                   float* __restrict__ loss) {
    __shared__ float red[NBLK];
    int t = threadIdx.x;
    red[t] = partials[t];
    __syncthreads();
    for (int s = NBLK / 2; s > 0; s >>= 1) {
        if (t < s) red[t] += red[t + s];
        __syncthreads();
    }
    if (t == 0) loss[0] = red[0] * (1.25f / 8388608.0f);
}

extern "C" void kernel_launch(void* const* d_in, const int* in_sizes, int n_in,
                              void* d_out, int out_size, void* d_ws, size_t ws_size,
                              hipStream_t stream) {
    const float* z_e = (const float*)d_in[0];
    const float* emb = (const float*)d_in[1];

    float* out      = (float*)d_out;
    float* out_q    = out;
    float* out_idx  = out + 8388608;
    float* out_loss = out + 8388608 + 131072;

    char* w = (char*)d_ws;
    float*          E        = (float*)(w);                    //   4 KB
    unsigned short* e_swz    = (unsigned short*)(w + 4096);    // 256 KB
    int*            bestk    = (int*)(w + 266240);             // 512 KB
    int*            flagA    = (int*)(w + 790528);             // 512 KB
    int*            list     = (int*)(w + 1314816);            // 512 KB
    int*            cnt      = (int*)(w + 1839104);
    float*          partials = (float*)(w + 1840128);          //   2 KB

    vq_esq<<<KCODES / 256, 256, 0, stream>>>(emb, E);
    vq_eprep<<<KCODES / 256, 256, 0, stream>>>(emb, e_swz);
    vq_zero<<<1, 64, 0, stream>>>(cnt);
    vq_scan_mfma<<<NPTS / 128, 256, 0, stream>>>(z_e, e_swz, E, bestk, flagA);
    vq_compact<<<NPTS / 256, 256, 0, stream>>>(flagA, list, cnt);
    vq_rescue<<<2048, 256, 0, stream>>>(z_e, emb, E, list, cnt, bestk);
    vq_merge<<<NBLK, 256, 0, stream>>>(z_e, emb, bestk, out_q, out_idx, partials);
    vq_loss_fin<<<1, NBLK, 0, stream>>>(partials, out_loss);
}